// Round 13
// baseline (33.643 us; speedup 1.0000x reference)
//
#include <hip/hip_runtime.h>

// StructOnlyClassifier R13: R12 with GPW=1 -> 16,384 waves in 4,096 blocks
// (2x resident capacity). Block CHURN overlaps gen-2 waves' search prefixes
// with gen-1 waves' streaming (R12's exactly-resident grid ran all search
// prefixes simultaneously with memory idle). Layer-2 dot split across lane&16
// halves (16-step chain + 1 combine instead of 32-step).

constexpr int UNR = 5;     // 5*64 quads = 1280 nodes covered before fallback

__device__ __forceinline__ int interp_lower_bound(
    const int* __restrict__ batch, int n, int stride, int g)
{
    // first idx with batch[idx] >= g. Invariant: lb in [blo, bhi], 4-aligned.
    int blo = 0, bhi = n;
    long long pos = (long long)g * stride - (stride >> 1);
    int it = 0;
    while (bhi - blo > 4) {
        int p;
        if (it < 5) {                         // interpolation phase
            long long pc = pos;
            if (pc < blo) pc = blo;
            if (pc > bhi - 4) pc = bhi - 4;
            p = (int)pc & ~3;
            ++it;
        } else {                              // binary fallback
            p = ((blo + bhi) >> 1) & ~3;
            if (p > bhi - 4) p = bhi - 4;
        }
        const int4 q = *(const int4*)(batch + p);
        if (q.w < g) {
            blo = p + 4;
            pos = p + 4 + (long long)(g - q.w) * stride - (stride >> 1);
        } else if (q.x >= g) {
            bhi = p;
            pos = p + (long long)(g - q.x) * stride - (stride >> 1);
        } else {
            return p + 1 + (q.y < g) + (q.z < g);
        }
    }
    if (bhi > blo) {
        const int4 q = *(const int4*)(batch + blo);
        return blo + (q.x < g) + (q.y < g) + (q.z < g) + (q.w < g);
    }
    return blo;
}

__global__ __launch_bounds__(256) void fused_kernel(
    const int* __restrict__ batch, const int* __restrict__ ntype,
    const float* __restrict__ W1, const float* __restrict__ b1,
    const float* __restrict__ W2, const float* __restrict__ b2,
    const float* __restrict__ W3, const float* __restrict__ b3,
    float* __restrict__ out, int n, int B, int stride)
{
    __shared__ float sW1[128], sW2[512], sb1[32], sb2[16], sW3[16], sb3v[1];
    const int tid = threadIdx.x;
    if (tid < 128) sW1[tid] = W1[tid];
    sW2[tid]       = W2[tid];
    sW2[tid + 256] = W2[tid + 256];
    if      (tid < 32)  sb1[tid]      = b1[tid];
    else if (tid < 48)  sb2[tid - 32] = b2[tid - 32];
    else if (tid < 64)  sW3[tid - 48] = W3[tid - 48];
    else if (tid == 64) sb3v[0]       = b3[0];
    __syncthreads();

    const int g    = (blockIdx.x * 256 + tid) >> 6;   // one wave per graph
    const int lane = tid & 63;
    if (g >= B) return;

    // ---- boundary searches on lanes 0,1 (~4 probes each, independent) ----
    int ans = 0;
    if (lane <= 1) ans = interp_lower_bound(batch, n, stride, g + lane);
    const int s = __shfl(ans, 0);
    const int e = __shfl(ans, 1);
    const int len = e - s;

    // ---- stream count: fixed 5-deep independent clamped loads ----
    const int4* nt4 = (const int4*)ntype;
    const int nqm1 = (n >> 2) - 1;
    int c0 = 0, c1 = 0;

    int sa = (s + 3) & ~3; if (sa > e) sa = e;
    int ea = e & ~3;       if (ea < sa) ea = sa;

    {   // head scalars [s, sa): <=3 active lanes
        const int idx = s + lane;
        if (idx < sa) { const int v = ntype[idx]; c0 += (v == 0); c1 += (v == 1); }
    }
    const int qa = (sa >> 2) + lane;
    const int qe = (ea >> 2);
    #pragma unroll
    for (int u = 0; u < UNR; ++u) {           // independent clamped loads
        const int qi = qa + u * 64;
        const int4 v = nt4[min(qi, nqm1)];
        if (qi < qe) {
            c0 += (v.x == 0) + (v.y == 0) + (v.z == 0) + (v.w == 0);
            c1 += (v.x == 1) + (v.y == 1) + (v.z == 1) + (v.w == 1);
        }
    }
    for (int qi = qa + UNR * 64; qi < qe; qi += 64) {  // pathological fallback
        const int4 v = nt4[qi];
        c0 += (v.x == 0) + (v.y == 0) + (v.z == 0) + (v.w == 0);
        c1 += (v.x == 1) + (v.y == 1) + (v.z == 1) + (v.w == 1);
    }
    {   // tail scalars [ea, e): <=3 active lanes
        const int idx = ea + lane;
        if (idx < e) { const int v = ntype[idx]; c0 += (v == 0); c1 += (v == 1); }
    }

    // ---- wave reduce both counts packed in one u64 ----
    unsigned long long p = (unsigned)c0 | ((unsigned long long)(unsigned)c1 << 32);
    #pragma unroll
    for (int off = 32; off; off >>= 1) p += __shfl_xor(p, off);
    const int c0t = (int)(p & 0xFFFFFFFFull);
    const int c1t = (int)(p >> 32);

    const float f0 = (float)c0t - 54.5f;
    const float f1 = (float)c1t;
    const float f2 = (float)(len - c0t - c1t);
    const float f3 = (float)len - 56.5f;

    // layer 1: unit j on lane&31 (both halves hold identical h1)
    const int j = lane & 31;
    float h1 = sb1[j];
    h1 = fmaf(f0, sW1[      j], h1);
    h1 = fmaf(f1, sW1[ 32 + j], h1);
    h1 = fmaf(f2, sW1[ 64 + j], h1);
    h1 = fmaf(f3, sW1[ 96 + j], h1);
    h1 = fmaxf(0.0f, h1);

    // layer 2: unit m on lane&15; lane&16 halves split the 32-term dot
    const int m = lane & 15;
    const int jb = lane & 16;                  // 0 or 16
    float sm = 0.0f;
    #pragma unroll
    for (int jj = 0; jj < 16; ++jj)
        sm = fmaf(__shfl(h1, jb + jj), sW2[(jb + jj) * 16 + m], sm);
    sm += __shfl_xor(sm, 16);                  // combine the two halves
    const float h2 = fmaxf(0.0f, sm + sb2[m]);

    // layer 3: reduce 16 units within the 16-lane group
    float p3 = h2 * sW3[m];
    p3 += __shfl_xor(p3, 8);
    p3 += __shfl_xor(p3, 4);
    p3 += __shfl_xor(p3, 2);
    p3 += __shfl_xor(p3, 1);

    if (lane == 0) out[g] = p3 + sb3v[0];
}

extern "C" void kernel_launch(void* const* d_in, const int* in_sizes, int n_in,
                              void* d_out, int out_size, void* d_ws, size_t ws_size,
                              hipStream_t stream) {
    // inputs: 0:x(N) 1:batch(N) 2:node_type(N) 3:num_graphs 4:W1 5:b1 6:W2 7:b2 8:W3 9:b3
    const int*   batch = (const int*)d_in[1];
    const int*   ntype = (const int*)d_in[2];
    const float* W1    = (const float*)d_in[4];
    const float* b1    = (const float*)d_in[5];
    const float* W2    = (const float*)d_in[6];
    const float* b2    = (const float*)d_in[7];
    const float* W3    = (const float*)d_in[8];
    const float* b3    = (const float*)d_in[9];
    float*       out   = (float*)d_out;

    const int n = in_sizes[1];          // 16,777,216 nodes
    const int B = out_size;             // 16,384 graphs

    const int blocks = (B * 64 + 255) / 256;         // 4096 blocks, 16384 waves
    fused_kernel<<<blocks, 256, 0, stream>>>(
        batch, ntype, W1, b1, W2, b2, W3, b3, out, n, B, n / B);
}

// Round 14
// 27.237 us; speedup vs baseline: 1.2352x; 1.2352x over previous
//
#include <hip/hip_runtime.h>

// StructOnlyClassifier R14: R12 (best, 27.3us) + XCD-aware block swizzle (T1).
// Timed replays are warm-L3 (poison fill runs once; ~0 HBM bytes during
// replays). Default round-robin block->XCD mapping scatters adjacent data
// windows across XCDs -> no L2 reuse across replays. Swizzle gives each XCD a
// CONTIGUOUS 8 MiB ntype slice; its 4 MiB L2 retains ~half across replays,
// converting ~L3-latency hops (~600cy) into L2 hits (~200cy).
// Everything else byte-identical to R12's measured-best structure.

constexpr int GPW = 2;
constexpr int UNR = 5;     // 5*64 quads = 1280 nodes per graph before fallback

__device__ __forceinline__ int interp_lower_bound(
    const int* __restrict__ batch, int n, int stride, int g)
{
    // first idx with batch[idx] >= g. Invariant: lb in [blo, bhi], 4-aligned.
    int blo = 0, bhi = n;
    long long pos = (long long)g * stride - (stride >> 1);
    int it = 0;
    while (bhi - blo > 4) {
        int p;
        if (it < 5) {                         // interpolation phase
            long long pc = pos;
            if (pc < blo) pc = blo;
            if (pc > bhi - 4) pc = bhi - 4;
            p = (int)pc & ~3;
            ++it;
        } else {                              // binary fallback
            p = ((blo + bhi) >> 1) & ~3;
            if (p > bhi - 4) p = bhi - 4;
        }
        const int4 q = *(const int4*)(batch + p);
        if (q.w < g) {
            blo = p + 4;
            pos = p + 4 + (long long)(g - q.w) * stride - (stride >> 1);
        } else if (q.x >= g) {
            bhi = p;
            pos = p + (long long)(g - q.x) * stride - (stride >> 1);
        } else {
            return p + 1 + (q.y < g) + (q.z < g);
        }
    }
    if (bhi > blo) {
        const int4 q = *(const int4*)(batch + blo);
        return blo + (q.x < g) + (q.y < g) + (q.z < g) + (q.w < g);
    }
    return blo;
}

__global__ __launch_bounds__(256) void fused_kernel(
    const int* __restrict__ batch, const int* __restrict__ ntype,
    const float* __restrict__ W1, const float* __restrict__ b1,
    const float* __restrict__ W2, const float* __restrict__ b2,
    const float* __restrict__ W3, const float* __restrict__ b3,
    float* __restrict__ out, int n, int B, int stride)
{
    __shared__ float sW1[128], sW2[512], sb1[32], sb2[16], sW3[16], sb3v[1];
    const int tid = threadIdx.x;
    if (tid < 128) sW1[tid] = W1[tid];
    sW2[tid]       = W2[tid];
    sW2[tid + 256] = W2[tid + 256];
    if      (tid < 32)  sb1[tid]      = b1[tid];
    else if (tid < 48)  sb2[tid - 32] = b2[tid - 32];
    else if (tid < 64)  sW3[tid - 48] = W3[tid - 48];
    else if (tid == 64) sb3v[0]       = b3[0];
    __syncthreads();

    // XCD-aware bijective swizzle: round-robin dispatch (xcd = bid%8) ->
    // each XCD owns a CONTIGUOUS range of data-block indices.
    const int nwg = gridDim.x;                 // 2048, divisible by 8
    const int cpx = nwg >> 3;                  // blocks per XCD
    const int sb  = (blockIdx.x & 7) * cpx + (blockIdx.x >> 3);

    const int wid  = (sb * 256 + tid) >> 6;
    const int lane = tid & 63;
    const int g0   = wid * GPW;
    if (g0 >= B) return;

    // ---- boundary searches on lanes 0..2 (~4 probes each, independent) ----
    int ans = 0;
    if (lane <= GPW) ans = interp_lower_bound(batch, n, stride, min(g0 + lane, B));
    const int s0 = __shfl(ans, 0);
    const int s1 = __shfl(ans, 1);
    const int s2b = __shfl(ans, 2);

    // ---- phase 1: stream counts for BOTH graphs (independent loads) ----
    const int4* nt4 = (const int4*)ntype;
    const int nqm1 = (n >> 2) - 1;
    int c0[2] = {0, 0}, c1[2] = {0, 0};

    #pragma unroll
    for (int i = 0; i < 2; ++i) {
        const int s = (i == 0) ? s0 : s1;
        const int e = (i == 0) ? s1 : s2b;
        int sa = (s + 3) & ~3; if (sa > e) sa = e;
        int ea = e & ~3;       if (ea < sa) ea = sa;

        {   // head scalars [s, sa): <=3 active lanes
            const int idx = s + lane;
            if (idx < sa) { const int v = ntype[idx]; c0[i] += (v == 0); c1[i] += (v == 1); }
        }
        const int qa = (sa >> 2) + lane;
        const int qe = (ea >> 2);
        #pragma unroll
        for (int u = 0; u < UNR; ++u) {       // fixed-depth independent loads
            const int qi = qa + u * 64;
            const int4 v = nt4[min(qi, nqm1)];
            if (qi < qe) {
                c0[i] += (v.x == 0) + (v.y == 0) + (v.z == 0) + (v.w == 0);
                c1[i] += (v.x == 1) + (v.y == 1) + (v.z == 1) + (v.w == 1);
            }
        }
        for (int qi = qa + UNR * 64; qi < qe; qi += 64) {  // pathological fallback
            const int4 v = nt4[qi];
            c0[i] += (v.x == 0) + (v.y == 0) + (v.z == 0) + (v.w == 0);
            c1[i] += (v.x == 1) + (v.y == 1) + (v.z == 1) + (v.w == 1);
        }
        {   // tail scalars [ea, e): <=3 active lanes
            const int idx = ea + lane;
            if (idx < e) { const int v = ntype[idx]; c0[i] += (v == 0); c1[i] += (v == 1); }
        }
    }

    // ---- dual wave-reduce (chains interleave) ----
    unsigned long long pa = (unsigned)c0[0] | ((unsigned long long)(unsigned)c1[0] << 32);
    unsigned long long pb = (unsigned)c0[1] | ((unsigned long long)(unsigned)c1[1] << 32);
    #pragma unroll
    for (int off = 32; off; off >>= 1) {
        pa += __shfl_xor(pa, off);
        pb += __shfl_xor(pb, off);
    }

    // ---- phase 2: both MLPs concurrently (graph = lane>=32 half) ----
    const bool hb = (lane >= 32);
    const int c0t = hb ? (int)(pb & 0xFFFFFFFFull) : (int)(pa & 0xFFFFFFFFull);
    const int c1t = hb ? (int)(pb >> 32)           : (int)(pa >> 32);
    const int len = hb ? (s2b - s1)                : (s1 - s0);

    const float f0 = (float)c0t - 54.5f;
    const float f1 = (float)c1t;
    const float f2 = (float)(len - c0t - c1t);
    const float f3 = (float)len - 56.5f;

    // layer 1: unit j on lane&31, per half
    const int j = lane & 31;
    float h1 = sb1[j];
    h1 = fmaf(f0, sW1[      j], h1);
    h1 = fmaf(f1, sW1[ 32 + j], h1);
    h1 = fmaf(f2, sW1[ 64 + j], h1);
    h1 = fmaf(f3, sW1[ 96 + j], h1);
    h1 = fmaxf(0.0f, h1);

    // layer 2: unit m on lane&15, h1 broadcast half-locally
    const int m = lane & 15;
    const int hbase = lane & 32;
    float sm = sb2[m];
    #pragma unroll
    for (int jj = 0; jj < 32; ++jj)
        sm = fmaf(__shfl(h1, hbase + jj), sW2[jj * 16 + m], sm);
    const float h2 = fmaxf(0.0f, sm);

    // layer 3: reduce 16 units within the 16-lane group
    float p3 = h2 * sW3[m];
    p3 += __shfl_xor(p3, 8);
    p3 += __shfl_xor(p3, 4);
    p3 += __shfl_xor(p3, 2);
    p3 += __shfl_xor(p3, 1);

    if (lane == 0)                          out[g0]     = p3 + sb3v[0];
    if (lane == 32 && g0 + 1 < B)           out[g0 + 1] = p3 + sb3v[0];
}

extern "C" void kernel_launch(void* const* d_in, const int* in_sizes, int n_in,
                              void* d_out, int out_size, void* d_ws, size_t ws_size,
                              hipStream_t stream) {
    // inputs: 0:x(N) 1:batch(N) 2:node_type(N) 3:num_graphs 4:W1 5:b1 6:W2 7:b2 8:W3 9:b3
    const int*   batch = (const int*)d_in[1];
    const int*   ntype = (const int*)d_in[2];
    const float* W1    = (const float*)d_in[4];
    const float* b1    = (const float*)d_in[5];
    const float* W2    = (const float*)d_in[6];
    const float* b2    = (const float*)d_in[7];
    const float* W3    = (const float*)d_in[8];
    const float* b3    = (const float*)d_in[9];
    float*       out   = (float*)d_out;

    const int n = in_sizes[1];          // 16,777,216 nodes
    const int B = out_size;             // 16,384 graphs

    const int waves  = (B + GPW - 1) / GPW;          // 8192
    const int blocks = (waves * 64 + 255) / 256;     // 2048 (divisible by 8)
    fused_kernel<<<blocks, 256, 0, stream>>>(
        batch, ntype, W1, b1, W2, b2, W3, b3, out, n, B, n / B);
}

// Round 15
// 25.947 us; speedup vs baseline: 1.2966x; 1.0497x over previous
//
#include <hip/hip_runtime.h>

// StructOnlyClassifier R15: R12 skeleton (GPW=2, 8192 waves, interp search,
// fixed 5-deep loads, dual-half MLP) with per-wave overhead cut:
//  - block-shared boundary searches: 9 per block (threads 0-8 -> LDS), was 24
//  - layer-2 via LDS float4 (h1 staged in LDS, W2 transposed+padded [16][36]):
//    8 independent ds_read_b128 + 32 fma, replacing the 32-deep shfl chain
// Warm-replay profiling showed time is per-wave serial work, not memory
// traffic (warm dispatch == cold dispatch duration at 0 HBM bytes).

constexpr int GPW = 2;     // graphs per wave
constexpr int GPB = 8;     // graphs per block (4 waves)
constexpr int UNR = 5;     // 5*64 quads = 1280 nodes per graph before fallback

__device__ __forceinline__ int interp_lower_bound(
    const int* __restrict__ batch, int n, int stride, int g)
{
    // first idx with batch[idx] >= g. Invariant: lb in [blo, bhi], 4-aligned.
    int blo = 0, bhi = n;
    long long pos = (long long)g * stride - (stride >> 1);
    int it = 0;
    while (bhi - blo > 4) {
        int p;
        if (it < 5) {                         // interpolation phase
            long long pc = pos;
            if (pc < blo) pc = blo;
            if (pc > bhi - 4) pc = bhi - 4;
            p = (int)pc & ~3;
            ++it;
        } else {                              // binary fallback
            p = ((blo + bhi) >> 1) & ~3;
            if (p > bhi - 4) p = bhi - 4;
        }
        const int4 q = *(const int4*)(batch + p);
        if (q.w < g) {
            blo = p + 4;
            pos = p + 4 + (long long)(g - q.w) * stride - (stride >> 1);
        } else if (q.x >= g) {
            bhi = p;
            pos = p + (long long)(g - q.x) * stride - (stride >> 1);
        } else {
            return p + 1 + (q.y < g) + (q.z < g);
        }
    }
    if (bhi > blo) {
        const int4 q = *(const int4*)(batch + blo);
        return blo + (q.x < g) + (q.y < g) + (q.z < g) + (q.w < g);
    }
    return blo;
}

__global__ __launch_bounds__(256) void fused_kernel(
    const int* __restrict__ batch, const int* __restrict__ ntype,
    const float* __restrict__ W1, const float* __restrict__ b1,
    const float* __restrict__ W2, const float* __restrict__ b2,
    const float* __restrict__ W3, const float* __restrict__ b3,
    float* __restrict__ out, int n, int B, int stride)
{
    __shared__ float sW1[128], sb1[32], sb2[16], sW3[16], sb3v[1];
    __shared__ __attribute__((aligned(16))) float sW2T[16 * 36]; // [m][j] pad 36
    __shared__ __attribute__((aligned(16))) float sh1[4][2][32]; // [wave][half][j]
    __shared__ int sS[GPB + 1];

    const int tid = threadIdx.x;
    const int bi  = blockIdx.x;

    // ---- weight staging (issue loads first) ----
    if (tid < 128) sW1[tid] = W1[tid];
    for (int i = tid; i < 512; i += 256) {            // transpose W2 (32,16)
        const int j = i >> 4, m = i & 15;
        sW2T[m * 36 + j] = W2[i];
    }
    if      (tid < 32)  sb1[tid]      = b1[tid];
    else if (tid < 48)  sb2[tid - 32] = b2[tid - 32];
    else if (tid < 64)  sW3[tid - 48] = W3[tid - 48];
    else if (tid == 64) sb3v[0]       = b3[0];

    // ---- block-shared boundary searches: 9 per block ----
    if (tid <= GPB) {
        const int g = bi * GPB + tid;                 // <= B by construction
        sS[tid] = interp_lower_bound(batch, n, stride, g);
    }
    __syncthreads();

    const int w    = tid >> 6;
    const int lane = tid & 63;
    const int g0   = bi * GPB + w * GPW;

    const int s0  = sS[w * GPW];
    const int s1  = sS[w * GPW + 1];
    const int s2b = sS[w * GPW + 2];

    // ---- phase 1: stream counts for BOTH graphs (independent loads) ----
    const int4* nt4 = (const int4*)ntype;
    const int nqm1 = (n >> 2) - 1;
    int c0[2] = {0, 0}, c1[2] = {0, 0};

    #pragma unroll
    for (int i = 0; i < 2; ++i) {
        const int s = (i == 0) ? s0 : s1;
        const int e = (i == 0) ? s1 : s2b;
        int sa = (s + 3) & ~3; if (sa > e) sa = e;
        int ea = e & ~3;       if (ea < sa) ea = sa;

        {   // head scalars [s, sa): <=3 active lanes
            const int idx = s + lane;
            if (idx < sa) { const int v = ntype[idx]; c0[i] += (v == 0); c1[i] += (v == 1); }
        }
        const int qa = (sa >> 2) + lane;
        const int qe = (ea >> 2);
        #pragma unroll
        for (int u = 0; u < UNR; ++u) {       // fixed-depth independent loads
            const int qi = qa + u * 64;
            const int4 v = nt4[min(qi, nqm1)];
            if (qi < qe) {
                c0[i] += (v.x == 0) + (v.y == 0) + (v.z == 0) + (v.w == 0);
                c1[i] += (v.x == 1) + (v.y == 1) + (v.z == 1) + (v.w == 1);
            }
        }
        for (int qi = qa + UNR * 64; qi < qe; qi += 64) {  // pathological fallback
            const int4 v = nt4[qi];
            c0[i] += (v.x == 0) + (v.y == 0) + (v.z == 0) + (v.w == 0);
            c1[i] += (v.x == 1) + (v.y == 1) + (v.z == 1) + (v.w == 1);
        }
        {   // tail scalars [ea, e): <=3 active lanes
            const int idx = ea + lane;
            if (idx < e) { const int v = ntype[idx]; c0[i] += (v == 0); c1[i] += (v == 1); }
        }
    }

    // ---- dual wave-reduce (chains interleave) ----
    unsigned long long pa = (unsigned)c0[0] | ((unsigned long long)(unsigned)c1[0] << 32);
    unsigned long long pb = (unsigned)c0[1] | ((unsigned long long)(unsigned)c1[1] << 32);
    #pragma unroll
    for (int off = 32; off; off >>= 1) {
        pa += __shfl_xor(pa, off);
        pb += __shfl_xor(pb, off);
    }

    // ---- phase 2: both MLPs concurrently (graph = lane>=32 half) ----
    const bool hb = (lane >= 32);
    const int c0t = hb ? (int)(pb & 0xFFFFFFFFull) : (int)(pa & 0xFFFFFFFFull);
    const int c1t = hb ? (int)(pb >> 32)           : (int)(pa >> 32);
    const int len = hb ? (s2b - s1)                : (s1 - s0);

    const float f0 = (float)c0t - 54.5f;
    const float f1 = (float)c1t;
    const float f2 = (float)(len - c0t - c1t);
    const float f3 = (float)len - 56.5f;

    // layer 1: unit j on lane&31, per half
    const int j = lane & 31;
    float h1 = sb1[j];
    h1 = fmaf(f0, sW1[      j], h1);
    h1 = fmaf(f1, sW1[ 32 + j], h1);
    h1 = fmaf(f2, sW1[ 64 + j], h1);
    h1 = fmaf(f3, sW1[ 96 + j], h1);
    h1 = fmaxf(0.0f, h1);

    // layer 2: h1 through LDS; 8 independent float4 reads + 32 fma
    sh1[w][hb][j] = h1;           // 64 consecutive floats per wave: conflict-free
    __syncthreads();              // safety: cross-lane LDS visibility

    const int m = lane & 15;
    const float4* h4  = (const float4*)&sh1[w][hb][0];
    const float4* wt4 = (const float4*)&sW2T[m * 36];
    float sm = sb2[m];
    #pragma unroll
    for (int k = 0; k < 8; ++k) {
        const float4 a = h4[k];   // broadcast within half
        const float4 b = wt4[k];  // 2-way across halves: free
        sm = fmaf(a.x, b.x, sm);
        sm = fmaf(a.y, b.y, sm);
        sm = fmaf(a.z, b.z, sm);
        sm = fmaf(a.w, b.w, sm);
    }
    const float h2 = fmaxf(0.0f, sm);

    // layer 3: reduce 16 units within the 16-lane group
    float p3 = h2 * sW3[m];
    p3 += __shfl_xor(p3, 8);
    p3 += __shfl_xor(p3, 4);
    p3 += __shfl_xor(p3, 2);
    p3 += __shfl_xor(p3, 1);

    if (lane == 0)  out[g0]     = p3 + sb3v[0];
    if (lane == 32) out[g0 + 1] = p3 + sb3v[0];
}

extern "C" void kernel_launch(void* const* d_in, const int* in_sizes, int n_in,
                              void* d_out, int out_size, void* d_ws, size_t ws_size,
                              hipStream_t stream) {
    // inputs: 0:x(N) 1:batch(N) 2:node_type(N) 3:num_graphs 4:W1 5:b1 6:W2 7:b2 8:W3 9:b3
    const int*   batch = (const int*)d_in[1];
    const int*   ntype = (const int*)d_in[2];
    const float* W1    = (const float*)d_in[4];
    const float* b1    = (const float*)d_in[5];
    const float* W2    = (const float*)d_in[6];
    const float* b2    = (const float*)d_in[7];
    const float* W3    = (const float*)d_in[8];
    const float* b3    = (const float*)d_in[9];
    float*       out   = (float*)d_out;

    const int n = in_sizes[1];          // 16,777,216 nodes
    const int B = out_size;             // 16,384 graphs

    const int blocks = B / GPB;                      // 2048 blocks, 8192 waves
    fused_kernel<<<blocks, 256, 0, stream>>>(
        batch, ntype, W1, b1, W2, b2, W3, b3, out, n, B, n / B);
}

// Round 16
// 25.660 us; speedup vs baseline: 1.3111x; 1.0112x over previous
//
#include <hip/hip_runtime.h>

// StructOnlyClassifier R16: R15 minus wasted L3 traffic.
//  - overshoot loads clamped to the segment's own LAST quad (L1-hit, zero L3
//    traffic) instead of the array end (real far lines, ~20 MB/launch waste)
//  - wave-uniform skip of unroll iterations fully past the segment end
//  - layer-2 barrier dropped (sh1 is per-wave; same-wave LDS is ordered)
// Everything else identical to R15 (block-shared interp searches, LDS float4
// layer-2, GPW=2, 8192 waves).

constexpr int GPW = 2;     // graphs per wave
constexpr int GPB = 8;     // graphs per block (4 waves)
constexpr int UNR = 5;     // 5*64 quads = 1280 nodes per graph before fallback

__device__ __forceinline__ int interp_lower_bound(
    const int* __restrict__ batch, int n, int stride, int g)
{
    // first idx with batch[idx] >= g. Invariant: lb in [blo, bhi], 4-aligned.
    int blo = 0, bhi = n;
    long long pos = (long long)g * stride - (stride >> 1);
    int it = 0;
    while (bhi - blo > 4) {
        int p;
        if (it < 5) {                         // interpolation phase
            long long pc = pos;
            if (pc < blo) pc = blo;
            if (pc > bhi - 4) pc = bhi - 4;
            p = (int)pc & ~3;
            ++it;
        } else {                              // binary fallback
            p = ((blo + bhi) >> 1) & ~3;
            if (p > bhi - 4) p = bhi - 4;
        }
        const int4 q = *(const int4*)(batch + p);
        if (q.w < g) {
            blo = p + 4;
            pos = p + 4 + (long long)(g - q.w) * stride - (stride >> 1);
        } else if (q.x >= g) {
            bhi = p;
            pos = p + (long long)(g - q.x) * stride - (stride >> 1);
        } else {
            return p + 1 + (q.y < g) + (q.z < g);
        }
    }
    if (bhi > blo) {
        const int4 q = *(const int4*)(batch + blo);
        return blo + (q.x < g) + (q.y < g) + (q.z < g) + (q.w < g);
    }
    return blo;
}

__global__ __launch_bounds__(256) void fused_kernel(
    const int* __restrict__ batch, const int* __restrict__ ntype,
    const float* __restrict__ W1, const float* __restrict__ b1,
    const float* __restrict__ W2, const float* __restrict__ b2,
    const float* __restrict__ W3, const float* __restrict__ b3,
    float* __restrict__ out, int n, int B, int stride)
{
    __shared__ float sW1[128], sb1[32], sb2[16], sW3[16], sb3v[1];
    __shared__ __attribute__((aligned(16))) float sW2T[16 * 36]; // [m][j] pad 36
    __shared__ __attribute__((aligned(16))) float sh1[4][2][32]; // [wave][half][j]
    __shared__ int sS[GPB + 1];

    const int tid = threadIdx.x;
    const int bi  = blockIdx.x;

    // ---- weight staging (issue loads first) ----
    if (tid < 128) sW1[tid] = W1[tid];
    for (int i = tid; i < 512; i += 256) {            // transpose W2 (32,16)
        const int j = i >> 4, m = i & 15;
        sW2T[m * 36 + j] = W2[i];
    }
    if      (tid < 32)  sb1[tid]      = b1[tid];
    else if (tid < 48)  sb2[tid - 32] = b2[tid - 32];
    else if (tid < 64)  sW3[tid - 48] = W3[tid - 48];
    else if (tid == 64) sb3v[0]       = b3[0];

    // ---- block-shared boundary searches: 9 per block ----
    if (tid <= GPB) {
        const int g = bi * GPB + tid;                 // <= B by construction
        sS[tid] = interp_lower_bound(batch, n, stride, g);
    }
    __syncthreads();

    const int w    = tid >> 6;
    const int lane = tid & 63;
    const int g0   = bi * GPB + w * GPW;

    const int s0  = sS[w * GPW];
    const int s1  = sS[w * GPW + 1];
    const int s2b = sS[w * GPW + 2];

    // ---- phase 1: stream counts for BOTH graphs ----
    const int4* nt4 = (const int4*)ntype;
    int c0[2] = {0, 0}, c1[2] = {0, 0};

    #pragma unroll
    for (int i = 0; i < 2; ++i) {
        const int s = (i == 0) ? s0 : s1;
        const int e = (i == 0) ? s1 : s2b;
        int sa = (s + 3) & ~3; if (sa > e) sa = e;
        int ea = e & ~3;       if (ea < sa) ea = sa;

        {   // head scalars [s, sa): <=3 active lanes (line shared with stream)
            const int idx = s + lane;
            if (idx < sa) { const int v = ntype[idx]; c0[i] += (v == 0); c1[i] += (v == 1); }
        }
        const int qa    = (sa >> 2) + lane;
        const int qe    = (ea >> 2);
        const int qlast = max(qe - 1, 0);     // segment-local clamp target
        #pragma unroll
        for (int u = 0; u < UNR; ++u) {
            if (sa + u * 256 < ea) {          // wave-uniform: skip past-end iters
                const int qi = qa + u * 64;
                // inactive lanes clamp to the segment's own last quad ->
                // line already fetched by this wave: L1 hit, no L3 traffic
                const int4 v = nt4[min(qi, qlast)];
                if (qi < qe) {
                    c0[i] += (v.x == 0) + (v.y == 0) + (v.z == 0) + (v.w == 0);
                    c1[i] += (v.x == 1) + (v.y == 1) + (v.z == 1) + (v.w == 1);
                }
            }
        }
        for (int qi = qa + UNR * 64; qi < qe; qi += 64) {  // pathological fallback
            const int4 v = nt4[qi];
            c0[i] += (v.x == 0) + (v.y == 0) + (v.z == 0) + (v.w == 0);
            c1[i] += (v.x == 1) + (v.y == 1) + (v.z == 1) + (v.w == 1);
        }
        {   // tail scalars [ea, e): <=3 active lanes
            const int idx = ea + lane;
            if (idx < e) { const int v = ntype[idx]; c0[i] += (v == 0); c1[i] += (v == 1); }
        }
    }

    // ---- dual wave-reduce (chains interleave) ----
    unsigned long long pa = (unsigned)c0[0] | ((unsigned long long)(unsigned)c1[0] << 32);
    unsigned long long pb = (unsigned)c0[1] | ((unsigned long long)(unsigned)c1[1] << 32);
    #pragma unroll
    for (int off = 32; off; off >>= 1) {
        pa += __shfl_xor(pa, off);
        pb += __shfl_xor(pb, off);
    }

    // ---- phase 2: both MLPs concurrently (graph = lane>=32 half) ----
    const bool hb = (lane >= 32);
    const int c0t = hb ? (int)(pb & 0xFFFFFFFFull) : (int)(pa & 0xFFFFFFFFull);
    const int c1t = hb ? (int)(pb >> 32)           : (int)(pa >> 32);
    const int len = hb ? (s2b - s1)                : (s1 - s0);

    const float f0 = (float)c0t - 54.5f;
    const float f1 = (float)c1t;
    const float f2 = (float)(len - c0t - c1t);
    const float f3 = (float)len - 56.5f;

    // layer 1: unit j on lane&31, per half
    const int j = lane & 31;
    float h1 = sb1[j];
    h1 = fmaf(f0, sW1[      j], h1);
    h1 = fmaf(f1, sW1[ 32 + j], h1);
    h1 = fmaf(f2, sW1[ 64 + j], h1);
    h1 = fmaf(f3, sW1[ 96 + j], h1);
    h1 = fmaxf(0.0f, h1);

    // layer 2: h1 through per-wave LDS (same-wave: no barrier needed)
    sh1[w][hb][j] = h1;

    const int m = lane & 15;
    const float4* h4  = (const float4*)&sh1[w][hb][0];
    const float4* wt4 = (const float4*)&sW2T[m * 36];
    float sm = sb2[m];
    #pragma unroll
    for (int k = 0; k < 8; ++k) {
        const float4 a = h4[k];   // broadcast within half
        const float4 b = wt4[k];  // 2-way across halves: free
        sm = fmaf(a.x, b.x, sm);
        sm = fmaf(a.y, b.y, sm);
        sm = fmaf(a.z, b.z, sm);
        sm = fmaf(a.w, b.w, sm);
    }
    const float h2 = fmaxf(0.0f, sm);

    // layer 3: reduce 16 units within the 16-lane group
    float p3 = h2 * sW3[m];
    p3 += __shfl_xor(p3, 8);
    p3 += __shfl_xor(p3, 4);
    p3 += __shfl_xor(p3, 2);
    p3 += __shfl_xor(p3, 1);

    if (lane == 0)  out[g0]     = p3 + sb3v[0];
    if (lane == 32) out[g0 + 1] = p3 + sb3v[0];
}

extern "C" void kernel_launch(void* const* d_in, const int* in_sizes, int n_in,
                              void* d_out, int out_size, void* d_ws, size_t ws_size,
                              hipStream_t stream) {
    // inputs: 0:x(N) 1:batch(N) 2:node_type(N) 3:num_graphs 4:W1 5:b1 6:W2 7:b2 8:W3 9:b3
    const int*   batch = (const int*)d_in[1];
    const int*   ntype = (const int*)d_in[2];
    const float* W1    = (const float*)d_in[4];
    const float* b1    = (const float*)d_in[5];
    const float* W2    = (const float*)d_in[6];
    const float* b2    = (const float*)d_in[7];
    const float* W3    = (const float*)d_in[8];
    const float* b3    = (const float*)d_in[9];
    float*       out   = (float*)d_out;

    const int n = in_sizes[1];          // 16,777,216 nodes
    const int B = out_size;             // 16,384 graphs

    const int blocks = B / GPB;                      // 2048 blocks, 8192 waves
    fused_kernel<<<blocks, 256, 0, stream>>>(
        batch, ntype, W1, b1, W2, b2, W3, b3, out, n, B, n / B);
}

// Round 17
// 25.596 us; speedup vs baseline: 1.3144x; 1.0025x over previous
//
#include <hip/hip_runtime.h>

// StructOnlyClassifier R17: R16 with
//  - BRANCHLESS 5-deep unrolled loads (R12's issue shape): all 10 dwordx4
//    issue back-to-back (no scalar skip branches), clamped to the segment's
//    own last quad (R16's traffic fix -> L1 hits, no far lines)
//  - sum/parity counting: values in {0,1,2} => track s=sum(v), odd=sum(v&1);
//    c1=odd, c2=(s-odd)/2, c0=len-c1-c2. ~13 VALU/quad vs ~19.
// Everything else identical to R16 (block-shared interp searches, LDS float4
// layer-2, dual-half MLP, GPW=2, 8192 waves).

constexpr int GPW = 2;     // graphs per wave
constexpr int GPB = 8;     // graphs per block (4 waves)
constexpr int UNR = 5;     // 5*64 quads = 1280 nodes per graph before fallback

__device__ __forceinline__ int interp_lower_bound(
    const int* __restrict__ batch, int n, int stride, int g)
{
    // first idx with batch[idx] >= g. Invariant: lb in [blo, bhi], 4-aligned.
    int blo = 0, bhi = n;
    long long pos = (long long)g * stride - (stride >> 1);
    int it = 0;
    while (bhi - blo > 4) {
        int p;
        if (it < 5) {                         // interpolation phase
            long long pc = pos;
            if (pc < blo) pc = blo;
            if (pc > bhi - 4) pc = bhi - 4;
            p = (int)pc & ~3;
            ++it;
        } else {                              // binary fallback
            p = ((blo + bhi) >> 1) & ~3;
            if (p > bhi - 4) p = bhi - 4;
        }
        const int4 q = *(const int4*)(batch + p);
        if (q.w < g) {
            blo = p + 4;
            pos = p + 4 + (long long)(g - q.w) * stride - (stride >> 1);
        } else if (q.x >= g) {
            bhi = p;
            pos = p + (long long)(g - q.x) * stride - (stride >> 1);
        } else {
            return p + 1 + (q.y < g) + (q.z < g);
        }
    }
    if (bhi > blo) {
        const int4 q = *(const int4*)(batch + blo);
        return blo + (q.x < g) + (q.y < g) + (q.z < g) + (q.w < g);
    }
    return blo;
}

__global__ __launch_bounds__(256) void fused_kernel(
    const int* __restrict__ batch, const int* __restrict__ ntype,
    const float* __restrict__ W1, const float* __restrict__ b1,
    const float* __restrict__ W2, const float* __restrict__ b2,
    const float* __restrict__ W3, const float* __restrict__ b3,
    float* __restrict__ out, int n, int B, int stride)
{
    __shared__ float sW1[128], sb1[32], sb2[16], sW3[16], sb3v[1];
    __shared__ __attribute__((aligned(16))) float sW2T[16 * 36]; // [m][j] pad 36
    __shared__ __attribute__((aligned(16))) float sh1[4][2][32]; // [wave][half][j]
    __shared__ int sS[GPB + 1];

    const int tid = threadIdx.x;
    const int bi  = blockIdx.x;

    // ---- weight staging (issue loads first) ----
    if (tid < 128) sW1[tid] = W1[tid];
    for (int i = tid; i < 512; i += 256) {            // transpose W2 (32,16)
        const int j = i >> 4, m = i & 15;
        sW2T[m * 36 + j] = W2[i];
    }
    if      (tid < 32)  sb1[tid]      = b1[tid];
    else if (tid < 48)  sb2[tid - 32] = b2[tid - 32];
    else if (tid < 64)  sW3[tid - 48] = W3[tid - 48];
    else if (tid == 64) sb3v[0]       = b3[0];

    // ---- block-shared boundary searches: 9 per block ----
    if (tid <= GPB) {
        const int g = bi * GPB + tid;                 // <= B by construction
        sS[tid] = interp_lower_bound(batch, n, stride, g);
    }
    __syncthreads();

    const int w    = tid >> 6;
    const int lane = tid & 63;
    const int g0   = bi * GPB + w * GPW;

    const int s0  = sS[w * GPW];
    const int s1  = sS[w * GPW + 1];
    const int s2b = sS[w * GPW + 2];

    // ---- phase 1: stream counts (s = sum(v), odd = sum(v&1)) ----
    const int4* nt4 = (const int4*)ntype;
    int ss[2] = {0, 0}, oo[2] = {0, 0};

    #pragma unroll
    for (int i = 0; i < 2; ++i) {
        const int s = (i == 0) ? s0 : s1;
        const int e = (i == 0) ? s1 : s2b;
        int sa = (s + 3) & ~3; if (sa > e) sa = e;
        int ea = e & ~3;       if (ea < sa) ea = sa;

        {   // head scalars [s, sa): <=3 active lanes
            const int idx = s + lane;
            if (idx < sa) { const int v = ntype[idx]; ss[i] += v; oo[i] += v & 1; }
        }
        const int qa    = (sa >> 2) + lane;
        const int qe    = (ea >> 2);
        const int qlast = max(qe - 1, 0);     // segment-local clamp target
        #pragma unroll
        for (int u = 0; u < UNR; ++u) {       // branchless: all loads batch-issue
            const int qi = qa + u * 64;
            const int4 v = nt4[min(qi, qlast)];   // inactive -> own last quad (L1)
            if (qi < qe) {                        // per-lane predication (cndmask)
                ss[i] += (v.x + v.y) + (v.z + v.w);
                oo[i] += ((v.x & 1) + (v.y & 1)) + ((v.z & 1) + (v.w & 1));
            }
        }
        for (int qi = qa + UNR * 64; qi < qe; qi += 64) {  // pathological fallback
            const int4 v = nt4[qi];
            ss[i] += (v.x + v.y) + (v.z + v.w);
            oo[i] += ((v.x & 1) + (v.y & 1)) + ((v.z & 1) + (v.w & 1));
        }
        {   // tail scalars [ea, e): <=3 active lanes
            const int idx = ea + lane;
            if (idx < e) { const int v = ntype[idx]; ss[i] += v; oo[i] += v & 1; }
        }
    }

    // ---- dual wave-reduce (chains interleave) ----
    unsigned long long pa = (unsigned)ss[0] | ((unsigned long long)(unsigned)oo[0] << 32);
    unsigned long long pb = (unsigned)ss[1] | ((unsigned long long)(unsigned)oo[1] << 32);
    #pragma unroll
    for (int off = 32; off; off >>= 1) {
        pa += __shfl_xor(pa, off);
        pb += __shfl_xor(pb, off);
    }

    // ---- phase 2: both MLPs concurrently (graph = lane>=32 half) ----
    const bool hb = (lane >= 32);
    const int sT  = hb ? (int)(pb & 0xFFFFFFFFull) : (int)(pa & 0xFFFFFFFFull);
    const int oT  = hb ? (int)(pb >> 32)           : (int)(pa >> 32);
    const int len = hb ? (s2b - s1)                : (s1 - s0);

    const int c1t = oT;                 // count(v==1)
    const int c2t = (sT - oT) >> 1;     // count(v==2)

    const float f0 = (float)(len - c1t - c2t) - 54.5f;
    const float f1 = (float)c1t;
    const float f2 = (float)c2t;
    const float f3 = (float)len - 56.5f;

    // layer 1: unit j on lane&31, per half
    const int j = lane & 31;
    float h1 = sb1[j];
    h1 = fmaf(f0, sW1[      j], h1);
    h1 = fmaf(f1, sW1[ 32 + j], h1);
    h1 = fmaf(f2, sW1[ 64 + j], h1);
    h1 = fmaf(f3, sW1[ 96 + j], h1);
    h1 = fmaxf(0.0f, h1);

    // layer 2: h1 through per-wave LDS (same-wave: no barrier needed)
    sh1[w][hb][j] = h1;

    const int m = lane & 15;
    const float4* h4  = (const float4*)&sh1[w][hb][0];
    const float4* wt4 = (const float4*)&sW2T[m * 36];
    float sm = sb2[m];
    #pragma unroll
    for (int k = 0; k < 8; ++k) {
        const float4 a = h4[k];   // broadcast within half
        const float4 b = wt4[k];  // 2-way across halves: free
        sm = fmaf(a.x, b.x, sm);
        sm = fmaf(a.y, b.y, sm);
        sm = fmaf(a.z, b.z, sm);
        sm = fmaf(a.w, b.w, sm);
    }
    const float h2 = fmaxf(0.0f, sm);

    // layer 3: reduce 16 units within the 16-lane group
    float p3 = h2 * sW3[m];
    p3 += __shfl_xor(p3, 8);
    p3 += __shfl_xor(p3, 4);
    p3 += __shfl_xor(p3, 2);
    p3 += __shfl_xor(p3, 1);

    if (lane == 0)  out[g0]     = p3 + sb3v[0];
    if (lane == 32) out[g0 + 1] = p3 + sb3v[0];
}

extern "C" void kernel_launch(void* const* d_in, const int* in_sizes, int n_in,
                              void* d_out, int out_size, void* d_ws, size_t ws_size,
                              hipStream_t stream) {
    // inputs: 0:x(N) 1:batch(N) 2:node_type(N) 3:num_graphs 4:W1 5:b1 6:W2 7:b2 8:W3 9:b3
    const int*   batch = (const int*)d_in[1];
    const int*   ntype = (const int*)d_in[2];
    const float* W1    = (const float*)d_in[4];
    const float* b1    = (const float*)d_in[5];
    const float* W2    = (const float*)d_in[6];
    const float* b2    = (const float*)d_in[7];
    const float* W3    = (const float*)d_in[8];
    const float* b3    = (const float*)d_in[9];
    float*       out   = (float*)d_out;

    const int n = in_sizes[1];          // 16,777,216 nodes
    const int B = out_size;             // 16,384 graphs

    const int blocks = B / GPB;                      // 2048 blocks, 8192 waves
    fused_kernel<<<blocks, 256, 0, stream>>>(
        batch, ntype, W1, b1, W2, b2, W3, b3, out, n, B, n / B);
}

// Round 18
// 24.676 us; speedup vs baseline: 1.3634x; 1.0373x over previous
//
#include <hip/hip_runtime.h>

// StructOnlyClassifier R18: R17 with the dual u64 wave-reduce replaced by a
// SINGLE packed-u64 reduce: (sA,oA,sB,oB) as 4x16-bit fields (per-lane values
// <=40 pre-reduce, <=~2600 post-reduce -> no overflow). Halves the cross-lane
// DS ops (24->12) and u64 adds on the per-wave serial chain.
// Everything else identical to R17 (block-shared interp searches, branchless
// clamped 5-deep loads, sum/parity counting, LDS float4 layer-2, dual-half MLP).

constexpr int GPW = 2;     // graphs per wave
constexpr int GPB = 8;     // graphs per block (4 waves)
constexpr int UNR = 5;     // 5*64 quads = 1280 nodes per graph before fallback

__device__ __forceinline__ int interp_lower_bound(
    const int* __restrict__ batch, int n, int stride, int g)
{
    // first idx with batch[idx] >= g. Invariant: lb in [blo, bhi], 4-aligned.
    int blo = 0, bhi = n;
    long long pos = (long long)g * stride - (stride >> 1);
    int it = 0;
    while (bhi - blo > 4) {
        int p;
        if (it < 5) {                         // interpolation phase
            long long pc = pos;
            if (pc < blo) pc = blo;
            if (pc > bhi - 4) pc = bhi - 4;
            p = (int)pc & ~3;
            ++it;
        } else {                              // binary fallback
            p = ((blo + bhi) >> 1) & ~3;
            if (p > bhi - 4) p = bhi - 4;
        }
        const int4 q = *(const int4*)(batch + p);
        if (q.w < g) {
            blo = p + 4;
            pos = p + 4 + (long long)(g - q.w) * stride - (stride >> 1);
        } else if (q.x >= g) {
            bhi = p;
            pos = p + (long long)(g - q.x) * stride - (stride >> 1);
        } else {
            return p + 1 + (q.y < g) + (q.z < g);
        }
    }
    if (bhi > blo) {
        const int4 q = *(const int4*)(batch + blo);
        return blo + (q.x < g) + (q.y < g) + (q.z < g) + (q.w < g);
    }
    return blo;
}

__global__ __launch_bounds__(256) void fused_kernel(
    const int* __restrict__ batch, const int* __restrict__ ntype,
    const float* __restrict__ W1, const float* __restrict__ b1,
    const float* __restrict__ W2, const float* __restrict__ b2,
    const float* __restrict__ W3, const float* __restrict__ b3,
    float* __restrict__ out, int n, int B, int stride)
{
    __shared__ float sW1[128], sb1[32], sb2[16], sW3[16], sb3v[1];
    __shared__ __attribute__((aligned(16))) float sW2T[16 * 36]; // [m][j] pad 36
    __shared__ __attribute__((aligned(16))) float sh1[4][2][32]; // [wave][half][j]
    __shared__ int sS[GPB + 1];

    const int tid = threadIdx.x;
    const int bi  = blockIdx.x;

    // ---- weight staging (issue loads first) ----
    if (tid < 128) sW1[tid] = W1[tid];
    for (int i = tid; i < 512; i += 256) {            // transpose W2 (32,16)
        const int j = i >> 4, m = i & 15;
        sW2T[m * 36 + j] = W2[i];
    }
    if      (tid < 32)  sb1[tid]      = b1[tid];
    else if (tid < 48)  sb2[tid - 32] = b2[tid - 32];
    else if (tid < 64)  sW3[tid - 48] = W3[tid - 48];
    else if (tid == 64) sb3v[0]       = b3[0];

    // ---- block-shared boundary searches: 9 per block ----
    if (tid <= GPB) {
        const int g = bi * GPB + tid;                 // <= B by construction
        sS[tid] = interp_lower_bound(batch, n, stride, g);
    }
    __syncthreads();

    const int w    = tid >> 6;
    const int lane = tid & 63;
    const int g0   = bi * GPB + w * GPW;

    const int s0  = sS[w * GPW];
    const int s1  = sS[w * GPW + 1];
    const int s2b = sS[w * GPW + 2];

    // ---- phase 1: stream counts, packed (sA,oA,sB,oB) 4x16-bit in one u64 ----
    const int4* nt4 = (const int4*)ntype;
    unsigned long long pk = 0ull;    // [0:16)=sA [16:32)=oA [32:48)=sB [48:64)=oB

    #pragma unroll
    for (int i = 0; i < 2; ++i) {
        const int s = (i == 0) ? s0 : s1;
        const int e = (i == 0) ? s1 : s2b;
        const int shift = i ? 32 : 0;
        int sa = (s + 3) & ~3; if (sa > e) sa = e;
        int ea = e & ~3;       if (ea < sa) ea = sa;

        int ssum = 0, osum = 0;
        {   // head scalars [s, sa): <=3 active lanes
            const int idx = s + lane;
            if (idx < sa) { const int v = ntype[idx]; ssum += v; osum += v & 1; }
        }
        const int qa    = (sa >> 2) + lane;
        const int qe    = (ea >> 2);
        const int qlast = max(qe - 1, 0);     // segment-local clamp target
        #pragma unroll
        for (int u = 0; u < UNR; ++u) {       // branchless: all loads batch-issue
            const int qi = qa + u * 64;
            const int4 v = nt4[min(qi, qlast)];   // inactive -> own last quad (L1)
            if (qi < qe) {                        // per-lane predication (cndmask)
                ssum += (v.x + v.y) + (v.z + v.w);
                osum += ((v.x & 1) + (v.y & 1)) + ((v.z & 1) + (v.w & 1));
            }
        }
        for (int qi = qa + UNR * 64; qi < qe; qi += 64) {  // pathological fallback
            const int4 v = nt4[qi];
            ssum += (v.x + v.y) + (v.z + v.w);
            osum += ((v.x & 1) + (v.y & 1)) + ((v.z & 1) + (v.w & 1));
        }
        {   // tail scalars [ea, e): <=3 active lanes
            const int idx = ea + lane;
            if (idx < e) { const int v = ntype[idx]; ssum += v; osum += v & 1; }
        }
        pk += ((unsigned long long)(unsigned)ssum << shift)
            | ((unsigned long long)(unsigned)osum << (shift + 16));
    }

    // ---- single packed wave-reduce (6 levels, one u64 chain) ----
    #pragma unroll
    for (int off = 32; off; off >>= 1) pk += __shfl_xor(pk, off);

    // ---- phase 2: both MLPs concurrently (graph = lane>=32 half) ----
    const bool hb = (lane >= 32);
    const int sT  = hb ? (int)((pk >> 32) & 0xFFFFull) : (int)(pk & 0xFFFFull);
    const int oT  = hb ? (int)((pk >> 48) & 0xFFFFull) : (int)((pk >> 16) & 0xFFFFull);
    const int len = hb ? (s2b - s1)                    : (s1 - s0);

    const int c1t = oT;                 // count(v==1)
    const int c2t = (sT - oT) >> 1;     // count(v==2)

    const float f0 = (float)(len - c1t - c2t) - 54.5f;
    const float f1 = (float)c1t;
    const float f2 = (float)c2t;
    const float f3 = (float)len - 56.5f;

    // layer 1: unit j on lane&31, per half
    const int j = lane & 31;
    float h1 = sb1[j];
    h1 = fmaf(f0, sW1[      j], h1);
    h1 = fmaf(f1, sW1[ 32 + j], h1);
    h1 = fmaf(f2, sW1[ 64 + j], h1);
    h1 = fmaf(f3, sW1[ 96 + j], h1);
    h1 = fmaxf(0.0f, h1);

    // layer 2: h1 through per-wave LDS (same-wave: no barrier needed)
    sh1[w][hb][j] = h1;

    const int m = lane & 15;
    const float4* h4  = (const float4*)&sh1[w][hb][0];
    const float4* wt4 = (const float4*)&sW2T[m * 36];
    float sm = sb2[m];
    #pragma unroll
    for (int k = 0; k < 8; ++k) {
        const float4 a = h4[k];   // broadcast within half
        const float4 b = wt4[k];  // 2-way across halves: free
        sm = fmaf(a.x, b.x, sm);
        sm = fmaf(a.y, b.y, sm);
        sm = fmaf(a.z, b.z, sm);
        sm = fmaf(a.w, b.w, sm);
    }
    const float h2 = fmaxf(0.0f, sm);

    // layer 3: reduce 16 units within the 16-lane group
    float p3 = h2 * sW3[m];
    p3 += __shfl_xor(p3, 8);
    p3 += __shfl_xor(p3, 4);
    p3 += __shfl_xor(p3, 2);
    p3 += __shfl_xor(p3, 1);

    if (lane == 0)  out[g0]     = p3 + sb3v[0];
    if (lane == 32) out[g0 + 1] = p3 + sb3v[0];
}

extern "C" void kernel_launch(void* const* d_in, const int* in_sizes, int n_in,
                              void* d_out, int out_size, void* d_ws, size_t ws_size,
                              hipStream_t stream) {
    // inputs: 0:x(N) 1:batch(N) 2:node_type(N) 3:num_graphs 4:W1 5:b1 6:W2 7:b2 8:W3 9:b3
    const int*   batch = (const int*)d_in[1];
    const int*   ntype = (const int*)d_in[2];
    const float* W1    = (const float*)d_in[4];
    const float* b1    = (const float*)d_in[5];
    const float* W2    = (const float*)d_in[6];
    const float* b2    = (const float*)d_in[7];
    const float* W3    = (const float*)d_in[8];
    const float* b3    = (const float*)d_in[9];
    float*       out   = (float*)d_out;

    const int n = in_sizes[1];          // 16,777,216 nodes
    const int B = out_size;             // 16,384 graphs

    const int blocks = B / GPB;                      // 2048 blocks, 8192 waves
    fused_kernel<<<blocks, 256, 0, stream>>>(
        batch, ntype, W1, b1, W2, b2, W3, b3, out, n, B, n / B);
}